// Round 1
// baseline (373479.980 us; speedup 1.0000x reference)
//
#include <hip/hip_runtime.h>
#include <math.h>

// Problem: h_t = tanh(A h_{t-1} + B x_t + c), A = 0.9 I + 0.1 A_raw
// T=16384, X=512, H=1024, all fp32. Output: all h_t, [T, H].
//
// Phase 1: Bx = x @ B^T + c  -> written IN-PLACE into d_out (row t consumed
//          exactly once at step t, then overwritten by h_t).
// Phase 2: sequential scan, 256 blocks x 256 threads (1 block/CU -> all
//          co-resident), wave w of block b owns row r = 4b+w. A row held in
//          registers (16 floats/lane). Per step: agent-scope loads of h_prev
//          (cross-XCD coherent via LLC), shuffle reduce, tanh, agent store,
//          versioned-flag grid barrier.

#define T_STEPS 16384
#define XD 512
#define HD 1024

// ---------------------------------------------------------------------------
// Phase 1: GEMM  out[t][i] = sum_k x[t][k] * B[i][k] + c[i]
// 64x64 tile, 256 threads, 4x4 micro-tile per thread, K-chunk 32.
// ---------------------------------------------------------------------------
__global__ __launch_bounds__(256) void gemm_bx_kernel(
    const float* __restrict__ x, const float* __restrict__ B,
    const float* __restrict__ c, float* __restrict__ out)
{
    __shared__ __align__(16) float xs[32][68];  // [k][t], stride 68 floats (16B aligned rows)
    __shared__ __align__(16) float bs[32][68];  // [k][i]

    const int tid = threadIdx.x;
    const int t0 = blockIdx.x * 64;
    const int i0 = blockIdx.y * 64;
    const int tx = tid & 15;        // i direction (4 outputs)
    const int ty = tid >> 4;        // t direction (4 outputs)
    const int lr = tid >> 3;        // staging row 0..31
    const int lc = (tid & 7) << 2;  // staging k 0,4,...,28

    float acc[4][4] = {{0.f}};

    for (int k0 = 0; k0 < XD; k0 += 32) {
        const float4 xa = *(const float4*)&x[(size_t)(t0 + lr) * XD + k0 + lc];
        const float4 xb = *(const float4*)&x[(size_t)(t0 + lr + 32) * XD + k0 + lc];
        const float4 ba = *(const float4*)&B[(size_t)(i0 + lr) * XD + k0 + lc];
        const float4 bb = *(const float4*)&B[(size_t)(i0 + lr + 32) * XD + k0 + lc];
        __syncthreads();  // previous chunk's compute done before overwrite
        xs[lc + 0][lr] = xa.x; xs[lc + 1][lr] = xa.y; xs[lc + 2][lr] = xa.z; xs[lc + 3][lr] = xa.w;
        xs[lc + 0][lr + 32] = xb.x; xs[lc + 1][lr + 32] = xb.y; xs[lc + 2][lr + 32] = xb.z; xs[lc + 3][lr + 32] = xb.w;
        bs[lc + 0][lr] = ba.x; bs[lc + 1][lr] = ba.y; bs[lc + 2][lr] = ba.z; bs[lc + 3][lr] = ba.w;
        bs[lc + 0][lr + 32] = bb.x; bs[lc + 1][lr + 32] = bb.y; bs[lc + 2][lr + 32] = bb.z; bs[lc + 3][lr + 32] = bb.w;
        __syncthreads();
        #pragma unroll
        for (int k = 0; k < 32; ++k) {
            const float4 av = *(const float4*)&xs[k][ty << 2];
            const float4 bv = *(const float4*)&bs[k][tx << 2];
            const float am[4] = {av.x, av.y, av.z, av.w};
            const float bn[4] = {bv.x, bv.y, bv.z, bv.w};
            #pragma unroll
            for (int m = 0; m < 4; ++m)
                #pragma unroll
                for (int n = 0; n < 4; ++n)
                    acc[m][n] = fmaf(am[m], bn[n], acc[m][n]);
        }
    }

    #pragma unroll
    for (int m = 0; m < 4; ++m) {
        const int trow = t0 + (ty << 2) + m;
        #pragma unroll
        for (int n = 0; n < 4; ++n) {
            const int icol = i0 + (tx << 2) + n;
            out[(size_t)trow * HD + icol] = acc[m][n] + c[icol];
        }
    }
}

// ---------------------------------------------------------------------------
// Flag init (d_ws is poisoned 0xAA before every launch)
// ---------------------------------------------------------------------------
__global__ void init_flags_kernel(int* flags)
{
    flags[threadIdx.x] = 0;
}

// ---------------------------------------------------------------------------
// Phase 2: sequential scan. 256 blocks x 256 threads. Wave (tid>>6) of block
// bid owns row r = 4*bid + wave. Lane l covers columns l, l+64, ..., l+960.
// ---------------------------------------------------------------------------
__global__ __launch_bounds__(256) void rnn_scan_kernel(
    const float* __restrict__ A_raw, const float* __restrict__ h0,
    float* out, int* flags)
{
    const int tid = threadIdx.x;
    const int bid = blockIdx.x;
    const int wave = tid >> 6;
    const int lane = tid & 63;
    const int r = bid * 4 + wave;   // owned row, 0..1023

    // Preload effective A row: A_eff[r][k] = 0.1*A_raw[r][k] + 0.9*(k==r)
    float aw[16];
    #pragma unroll
    for (int j = 0; j < 16; ++j) {
        const int k = lane + 64 * j;
        float v = 0.1f * A_raw[(size_t)r * HD + k];
        if (k == r) v += 0.9f;
        aw[j] = v;
    }

    for (int t = 0; t < T_STEPS; ++t) {
        float partial = 0.f;
        if (t == 0) {
            #pragma unroll
            for (int j = 0; j < 16; ++j)
                partial = fmaf(aw[j], h0[lane + 64 * j], partial);
        } else {
            const float* hp = out + (size_t)(t - 1) * HD;
            #pragma unroll
            for (int j = 0; j < 16; ++j) {
                // agent-scope load: bypasses non-coherent L1/L2, reads LLC
                const float hv = __hip_atomic_load((float*)(hp + lane + 64 * j),
                                                   __ATOMIC_RELAXED,
                                                   __HIP_MEMORY_SCOPE_AGENT);
                partial = fmaf(aw[j], hv, partial);
            }
        }

        // wave-wide sum (64 lanes)
        #pragma unroll
        for (int off = 32; off >= 1; off >>= 1)
            partial += __shfl_xor(partial, off, 64);

        if (lane == 0) {
            const float bx = out[(size_t)t * HD + r];  // own Bx element, consumed once
            const float hv = tanhf(partial + bx);
            __hip_atomic_store(out + (size_t)t * HD + r, hv,
                               __ATOMIC_RELAXED, __HIP_MEMORY_SCOPE_AGENT);
        }

        // Grid barrier via monotonic versioned flags.
        // __syncthreads drains vmcnt -> all 4 h-stores of this block are at the
        // LLC before the release flag store below.
        __syncthreads();
        if (tid == 0)
            __hip_atomic_store(&flags[bid], t + 1,
                               __ATOMIC_RELEASE, __HIP_MEMORY_SCOPE_AGENT);
        while (__hip_atomic_load(&flags[tid], __ATOMIC_ACQUIRE,
                                 __HIP_MEMORY_SCOPE_AGENT) < t + 1) {}
        __syncthreads();
    }
}

// ---------------------------------------------------------------------------
extern "C" void kernel_launch(void* const* d_in, const int* in_sizes, int n_in,
                              void* d_out, int out_size, void* d_ws, size_t ws_size,
                              hipStream_t stream)
{
    const float* x     = (const float*)d_in[0];  // [16384, 512]
    const float* h0    = (const float*)d_in[1];  // [1024]
    const float* A_raw = (const float*)d_in[2];  // [1024, 1024]
    const float* B     = (const float*)d_in[3];  // [1024, 512]
    const float* c     = (const float*)d_in[4];  // [1024]
    float* out = (float*)d_out;                  // [16384, 1024]
    int* flags = (int*)d_ws;                     // 256 ints

    dim3 gemm_grid(T_STEPS / 64, HD / 64);       // 256 x 16
    gemm_bx_kernel<<<gemm_grid, 256, 0, stream>>>(x, B, c, out);
    init_flags_kernel<<<1, 256, 0, stream>>>(flags);
    rnn_scan_kernel<<<256, 256, 0, stream>>>(A_raw, h0, out, flags);
}

// Round 2
// 126199.841 us; speedup vs baseline: 2.9594x; 2.9594x over previous
//
#include <hip/hip_runtime.h>
#include <math.h>

// Problem: h_t = tanh(A h_{t-1} + B x_t + c), A = 0.9 I + 0.1 A_raw
// T=16384, X=512, H=1024, all fp32. Output: all h_t, [T, H].
//
// Phase 1: Bx = x @ B^T + c  -> written IN-PLACE into d_out (row t consumed
//          exactly once at step t, then overwritten by h_t).
// Phase 2: sequential scan, 256 blocks x 256 threads (1 block/CU -> all
//          co-resident), wave w of block b owns row r = 4b+w. A row held in
//          registers (16 floats/lane). Per step: agent-scope bypass loads of
//          h_prev (LLC-coherent across XCDs), batched for ILP, shuffle
//          reduce, tanh, agent store, versioned-flag grid barrier with
//          RELAXED polling (no per-iteration cache maintenance).

#define T_STEPS 16384
#define XD 512
#define HD 1024

// ---------------------------------------------------------------------------
// Phase 1: GEMM  out[t][i] = sum_k x[t][k] * B[i][k] + c[i]
// 64x64 tile, 256 threads, 4x4 micro-tile per thread, K-chunk 32.
// ---------------------------------------------------------------------------
__global__ __launch_bounds__(256) void gemm_bx_kernel(
    const float* __restrict__ x, const float* __restrict__ B,
    const float* __restrict__ c, float* __restrict__ out)
{
    __shared__ __align__(16) float xs[32][68];  // [k][t]
    __shared__ __align__(16) float bs[32][68];  // [k][i]

    const int tid = threadIdx.x;
    const int t0 = blockIdx.x * 64;
    const int i0 = blockIdx.y * 64;
    const int tx = tid & 15;        // i direction (4 outputs)
    const int ty = tid >> 4;        // t direction (4 outputs)
    const int lr = tid >> 3;        // staging row 0..31
    const int lc = (tid & 7) << 2;  // staging k 0,4,...,28

    float acc[4][4] = {{0.f}};

    for (int k0 = 0; k0 < XD; k0 += 32) {
        const float4 xa = *(const float4*)&x[(size_t)(t0 + lr) * XD + k0 + lc];
        const float4 xb = *(const float4*)&x[(size_t)(t0 + lr + 32) * XD + k0 + lc];
        const float4 ba = *(const float4*)&B[(size_t)(i0 + lr) * XD + k0 + lc];
        const float4 bb = *(const float4*)&B[(size_t)(i0 + lr + 32) * XD + k0 + lc];
        __syncthreads();
        xs[lc + 0][lr] = xa.x; xs[lc + 1][lr] = xa.y; xs[lc + 2][lr] = xa.z; xs[lc + 3][lr] = xa.w;
        xs[lc + 0][lr + 32] = xb.x; xs[lc + 1][lr + 32] = xb.y; xs[lc + 2][lr + 32] = xb.z; xs[lc + 3][lr + 32] = xb.w;
        bs[lc + 0][lr] = ba.x; bs[lc + 1][lr] = ba.y; bs[lc + 2][lr] = ba.z; bs[lc + 3][lr] = ba.w;
        bs[lc + 0][lr + 32] = bb.x; bs[lc + 1][lr + 32] = bb.y; bs[lc + 2][lr + 32] = bb.z; bs[lc + 3][lr + 32] = bb.w;
        __syncthreads();
        #pragma unroll
        for (int k = 0; k < 32; ++k) {
            const float4 av = *(const float4*)&xs[k][ty << 2];
            const float4 bv = *(const float4*)&bs[k][tx << 2];
            const float am[4] = {av.x, av.y, av.z, av.w};
            const float bn[4] = {bv.x, bv.y, bv.z, bv.w};
            #pragma unroll
            for (int m = 0; m < 4; ++m)
                #pragma unroll
                for (int n = 0; n < 4; ++n)
                    acc[m][n] = fmaf(am[m], bn[n], acc[m][n]);
        }
    }

    #pragma unroll
    for (int m = 0; m < 4; ++m) {
        const int trow = t0 + (ty << 2) + m;
        #pragma unroll
        for (int n = 0; n < 4; ++n) {
            const int icol = i0 + (tx << 2) + n;
            out[(size_t)trow * HD + icol] = acc[m][n] + c[icol];
        }
    }
}

// ---------------------------------------------------------------------------
// Flag init (d_ws is poisoned 0xAA before every launch)
// ---------------------------------------------------------------------------
__global__ void init_flags_kernel(int* flags)
{
    flags[threadIdx.x] = 0;
}

// ---------------------------------------------------------------------------
// Phase 2: sequential scan. 256 blocks x 256 threads. Wave (tid>>6) of block
// bid owns row r = 4*bid + wave. Lane l covers columns l, l+64, ..., l+960.
// ---------------------------------------------------------------------------
__global__ __launch_bounds__(256) void rnn_scan_kernel(
    const float* __restrict__ A_raw, const float* __restrict__ h0,
    float* out, int* flags)
{
    const int tid = threadIdx.x;
    const int bid = blockIdx.x;
    const int wave = tid >> 6;
    const int lane = tid & 63;
    const int r = bid * 4 + wave;   // owned row, 0..1023

    // Preload effective A row: A_eff[r][k] = 0.1*A_raw[r][k] + 0.9*(k==r)
    float aw[16];
    #pragma unroll
    for (int j = 0; j < 16; ++j) {
        const int k = lane + 64 * j;
        float v = 0.1f * A_raw[(size_t)r * HD + k];
        if (k == r) v += 0.9f;
        aw[j] = v;
    }

    for (int t = 0; t < T_STEPS; ++t) {
        float hv[16];
        if (t == 0) {
            #pragma unroll
            for (int j = 0; j < 16; ++j)
                hv[j] = h0[lane + 64 * j];
        } else {
            const float* hp = out + (size_t)(t - 1) * HD;
            // Batch all 16 bypass loads -> one overlapped LLC latency,
            // not 16 serialized ones.
            #pragma unroll
            for (int j = 0; j < 16; ++j)
                hv[j] = __hip_atomic_load((float*)(hp + lane + 64 * j),
                                          __ATOMIC_RELAXED,
                                          __HIP_MEMORY_SCOPE_AGENT);
        }

        float partial = 0.f;
        #pragma unroll
        for (int j = 0; j < 16; ++j)
            partial = fmaf(aw[j], hv[j], partial);

        // wave-wide sum (64 lanes)
        #pragma unroll
        for (int off = 32; off >= 1; off >>= 1)
            partial += __shfl_xor(partial, off, 64);

        if (lane == 0) {
            const float bx = out[(size_t)t * HD + r];  // own Bx element, consumed once
            const float hnew = tanhf(partial + bx);
            __hip_atomic_store(out + (size_t)t * HD + r, hnew,
                               __ATOMIC_RELAXED, __HIP_MEMORY_SCOPE_AGENT);
        }

        // Grid barrier via monotonic versioned flags.
        // __syncthreads drains vmcnt -> all 4 h-stores of this block are at
        // the LLC before the release flag store below.
        __syncthreads();
        if (tid == 0)
            __hip_atomic_store(&flags[bid], t + 1,
                               __ATOMIC_RELEASE, __HIP_MEMORY_SCOPE_AGENT);
        // RELAXED polling: no per-iteration cache maintenance. Thread tid
        // tracks block tid; the trailing __syncthreads makes the barrier
        // complete (all 256 flags observed >= t+1 collectively).
        while (__hip_atomic_load(&flags[tid], __ATOMIC_RELAXED,
                                 __HIP_MEMORY_SCOPE_AGENT) < t + 1) {}
        asm volatile("" ::: "memory");  // no hoisting of next-step loads
        __syncthreads();
    }
}

// ---------------------------------------------------------------------------
extern "C" void kernel_launch(void* const* d_in, const int* in_sizes, int n_in,
                              void* d_out, int out_size, void* d_ws, size_t ws_size,
                              hipStream_t stream)
{
    const float* x     = (const float*)d_in[0];  // [16384, 512]
    const float* h0    = (const float*)d_in[1];  // [1024]
    const float* A_raw = (const float*)d_in[2];  // [1024, 1024]
    const float* B     = (const float*)d_in[3];  // [1024, 512]
    const float* c     = (const float*)d_in[4];  // [1024]
    float* out = (float*)d_out;                  // [16384, 1024]
    int* flags = (int*)d_ws;                     // 256 ints

    dim3 gemm_grid(T_STEPS / 64, HD / 64);       // 256 x 16
    gemm_bx_kernel<<<gemm_grid, 256, 0, stream>>>(x, B, c, out);
    init_flags_kernel<<<1, 256, 0, stream>>>(flags);
    rnn_scan_kernel<<<256, 256, 0, stream>>>(A_raw, h0, out, flags);
}

// Round 3
// 26763.983 us; speedup vs baseline: 13.9546x; 4.7153x over previous
//
#include <hip/hip_runtime.h>
#include <math.h>

// h_t = tanh(A h_{t-1} + B x_t + c), A = 0.9 I + 0.1 A_raw
// T=16384, X=512, H=1024, fp32. Output: all h_t, [T, H].
//
// Phase 1: Bx = x @ B^T + c written in-place into d_out (row t is consumed
//          exactly once at step t, then overwritten with h_t).
// Phase 2: barrier-free tagged-slot pipeline.
//   - 64 blocks x 1024 threads; wave w of block b owns row r = 16b + w.
//   - h_t element j lives in an 8B slot (fp32 bits, tag=t+1) in a 4-deep
//     ring of 1024-slot buffers in d_ws (h_t -> ring[t&3]); h0 has tag 0 in
//     ring[3]. Tags make stale data self-identifying, so there is NO grid
//     barrier and NO flags: thread i spins on slot i of ring[(t+3)&3] with a
//     single relaxed agent-scope (LLC-coherent, L1/L2-bypass) 8B load, drops
//     the value into LDS, __syncthreads, and all 16 waves compute from LDS.
//   - Dataflow bounds inter-block skew to 1 step, so a 4-deep ring can never
//     overwrite a buffer that any block may still read.
//   - Producer: lane 0 stores h to out (plain) and the tagged slot (relaxed
//     agent store = sc1 write-through to LLC; vmcnt-retired, no fence needed).
//   - Bx for step t+1 is prefetched during step t (HBM-cold otherwise).

#define T_STEPS 16384
#define XD 512
#define HD 1024

// ---------------------------------------------------------------------------
// Phase 1: GEMM  out[t][i] = sum_k x[t][k] * B[i][k] + c[i]
// 64x64 tile, 256 threads, 4x4 micro-tile per thread, K-chunk 32.
// ---------------------------------------------------------------------------
__global__ __launch_bounds__(256) void gemm_bx_kernel(
    const float* __restrict__ x, const float* __restrict__ B,
    const float* __restrict__ c, float* __restrict__ out)
{
    __shared__ __align__(16) float xs[32][68];  // [k][t]
    __shared__ __align__(16) float bs[32][68];  // [k][i]

    const int tid = threadIdx.x;
    const int t0 = blockIdx.x * 64;
    const int i0 = blockIdx.y * 64;
    const int tx = tid & 15;        // i direction (4 outputs)
    const int ty = tid >> 4;        // t direction (4 outputs)
    const int lr = tid >> 3;        // staging row 0..31
    const int lc = (tid & 7) << 2;  // staging k 0,4,...,28

    float acc[4][4] = {{0.f}};

    for (int k0 = 0; k0 < XD; k0 += 32) {
        const float4 xa = *(const float4*)&x[(size_t)(t0 + lr) * XD + k0 + lc];
        const float4 xb = *(const float4*)&x[(size_t)(t0 + lr + 32) * XD + k0 + lc];
        const float4 ba = *(const float4*)&B[(size_t)(i0 + lr) * XD + k0 + lc];
        const float4 bb = *(const float4*)&B[(size_t)(i0 + lr + 32) * XD + k0 + lc];
        __syncthreads();
        xs[lc + 0][lr] = xa.x; xs[lc + 1][lr] = xa.y; xs[lc + 2][lr] = xa.z; xs[lc + 3][lr] = xa.w;
        xs[lc + 0][lr + 32] = xb.x; xs[lc + 1][lr + 32] = xb.y; xs[lc + 2][lr + 32] = xb.z; xs[lc + 3][lr + 32] = xb.w;
        bs[lc + 0][lr] = ba.x; bs[lc + 1][lr] = ba.y; bs[lc + 2][lr] = ba.z; bs[lc + 3][lr] = ba.w;
        bs[lc + 0][lr + 32] = bb.x; bs[lc + 1][lr + 32] = bb.y; bs[lc + 2][lr + 32] = bb.z; bs[lc + 3][lr + 32] = bb.w;
        __syncthreads();
        #pragma unroll
        for (int k = 0; k < 32; ++k) {
            const float4 av = *(const float4*)&xs[k][ty << 2];
            const float4 bv = *(const float4*)&bs[k][tx << 2];
            const float am[4] = {av.x, av.y, av.z, av.w};
            const float bn[4] = {bv.x, bv.y, bv.z, bv.w};
            #pragma unroll
            for (int m = 0; m < 4; ++m)
                #pragma unroll
                for (int n = 0; n < 4; ++n)
                    acc[m][n] = fmaf(am[m], bn[n], acc[m][n]);
        }
    }

    #pragma unroll
    for (int m = 0; m < 4; ++m) {
        const int trow = t0 + (ty << 2) + m;
        #pragma unroll
        for (int n = 0; n < 4; ++n) {
            const int icol = i0 + (tx << 2) + n;
            out[(size_t)trow * HD + icol] = acc[m][n] + c[icol];
        }
    }
}

// ---------------------------------------------------------------------------
// Slot-ring init (d_ws is poisoned 0xAA before every launch).
// ring[3] holds h0 with tag 0; rings 0..2 get an impossible tag.
// ---------------------------------------------------------------------------
__global__ void init_slots_kernel(unsigned long long* slots, const float* h0)
{
    const int i = threadIdx.x;  // 1024 threads
    union { float f; unsigned u; } v; v.f = h0[i];
    slots[3 * HD + i] = (unsigned long long)v.u;          // tag 0 | h0 bits
    slots[0 * HD + i] = 0xFFFFFFFF00000000ull;
    slots[1 * HD + i] = 0xFFFFFFFF00000000ull;
    slots[2 * HD + i] = 0xFFFFFFFF00000000ull;
}

// ---------------------------------------------------------------------------
// Phase 2: tagged-slot scan. 64 blocks x 1024 threads, row r = 16*bid + wave.
// ---------------------------------------------------------------------------
__global__ __launch_bounds__(1024) void rnn_scan_kernel(
    const float* __restrict__ A_raw, float* out,
    unsigned long long* slots)
{
    const int tid = threadIdx.x;
    const int bid = blockIdx.x;
    const int wave = tid >> 6;
    const int lane = tid & 63;
    const int r = (bid << 4) + wave;   // owned row, 0..1023

    __shared__ float hlds[2][HD];

    // Preload effective A row: A_eff[r][k] = 0.1*A_raw[r][k] + 0.9*(k==r)
    float aw[16];
    #pragma unroll
    for (int j = 0; j < 16; ++j) {
        const int k = lane + (j << 6);
        float v = 0.1f * A_raw[(size_t)r * HD + k];
        if (k == r) v += 0.9f;
        aw[j] = v;
    }

    // Prefetch Bx for t=0 (row 0 of out).
    float bxn = out[r];

    for (int t = 0; t < T_STEPS; ++t) {
        const float bx = bxn;

        // Spin on my slot of h_{t-1}: ring[(t+3)&3], expected tag t.
        const unsigned long long* sp =
            slots + ((size_t)((t + 3) & 3) << 10) + tid;
        unsigned long long s;
        do {
            s = __hip_atomic_load((unsigned long long*)sp, __ATOMIC_RELAXED,
                                  __HIP_MEMORY_SCOPE_AGENT);
        } while ((unsigned)(s >> 32) != (unsigned)t);
        union { unsigned u; float f; } cv; cv.u = (unsigned)s;
        hlds[t & 1][tid] = cv.f;
        __syncthreads();

        // Prefetch next step's Bx while h broadcast is consumed.
        const int tn = (t + 1 < T_STEPS) ? (t + 1) : t;
        bxn = out[(size_t)tn * HD + r];

        // Row dot product from LDS (lane stride 1 -> 2-way alias, free).
        const float* hl = hlds[t & 1];
        float p = 0.f;
        #pragma unroll
        for (int j = 0; j < 16; ++j)
            p = fmaf(aw[j], hl[lane + (j << 6)], p);

        // wave-wide sum (64 lanes)
        #pragma unroll
        for (int off = 32; off >= 1; off >>= 1)
            p += __shfl_xor(p, off, 64);

        if (lane == 0) {
            const float hnew = tanhf(p + bx);
            out[(size_t)t * HD + r] = hnew;          // plain store, kernel-end flush
            union { float f; unsigned u; } hv; hv.f = hnew;
            const unsigned long long pkt =
                ((unsigned long long)(unsigned)(t + 1) << 32) | (unsigned long long)hv.u;
            __hip_atomic_store(slots + ((size_t)(t & 3) << 10) + r, pkt,
                               __ATOMIC_RELAXED, __HIP_MEMORY_SCOPE_AGENT);
        }
        // No grid barrier: tags + 4-deep ring + dataflow (skew <= 1) are
        // sufficient. LDS double buffer covers intra-block wave skew.
    }
}

// ---------------------------------------------------------------------------
extern "C" void kernel_launch(void* const* d_in, const int* in_sizes, int n_in,
                              void* d_out, int out_size, void* d_ws, size_t ws_size,
                              hipStream_t stream)
{
    const float* x     = (const float*)d_in[0];  // [16384, 512]
    const float* h0    = (const float*)d_in[1];  // [1024]
    const float* A_raw = (const float*)d_in[2];  // [1024, 1024]
    const float* B     = (const float*)d_in[3];  // [1024, 512]
    const float* c     = (const float*)d_in[4];  // [1024]
    float* out = (float*)d_out;                  // [16384, 1024]
    unsigned long long* slots = (unsigned long long*)d_ws;  // 4 x 1024 x 8B

    dim3 gemm_grid(T_STEPS / 64, HD / 64);       // 256 x 16
    gemm_bx_kernel<<<gemm_grid, 256, 0, stream>>>(x, B, c, out);
    init_slots_kernel<<<1, HD, 0, stream>>>(slots, h0);
    rnn_scan_kernel<<<64, 1024, 0, stream>>>(A_raw, out, slots);
}

// Round 4
// 24432.489 us; speedup vs baseline: 15.2862x; 1.0954x over previous
//
#include <hip/hip_runtime.h>
#include <math.h>

// h_t = tanh(A h_{t-1} + B x_t + c), A = 0.9 I + 0.1 A_raw
// T=16384, X=512, H=1024, fp32. Output: all h_t, [T, H].
//
// Phase 1: Bx = x @ B^T + c written in-place into d_out (row t consumed
//          exactly once at step t, then overwritten with h_t).
// Phase 2: barrier-free tagged-slot pipeline (validated round 3):
//   - 64 blocks x 512 threads; wave w (of 8) of block b owns rows
//     r0 = 16b + 2w and r0+1. Per-lane A storage: 2x16 floats.
//   - h_t element j is an 8B (value, tag=t+1) packet in a 4-deep ring of
//     1024-slot buffers (h_t -> ring[t&3]); h0 tag 0 in ring[3]. Tags make
//     stale data self-identifying: no grid barrier, no flags.
//   - Thread i polls slots 2i, 2i+1 with ONE global_load_dwordx4 sc0 sc1
//     (L1/L2 bypass -> LLC-coherent; inline asm because the compiler will
//     not cluster atomic loads - measured rounds 1-2).
//   - Detected values go to LDS (double-buffered), __syncthreads, each wave
//     reads h once from LDS and computes BOTH its rows (halves DS traffic).
//   - Producer lane 0 stores two output floats (float2) and both packets
//     with one global_store_dwordx4 sc0 sc1 (write-through to LLC).
//   - Skew between any two waves <= 1 step (dataflow + per-step barrier),
//     so a 4-deep ring can never overwrite live data.

#define T_STEPS 16384
#define XD 512
#define HD 1024

typedef unsigned int uint32x4 __attribute__((ext_vector_type(4)));

// ---------------------------------------------------------------------------
// Phase 1: GEMM  out[t][i] = sum_k x[t][k] * B[i][k] + c[i]
// 64x64 tile, 256 threads, 4x4 micro-tile per thread, K-chunk 32.
// ---------------------------------------------------------------------------
__global__ __launch_bounds__(256) void gemm_bx_kernel(
    const float* __restrict__ x, const float* __restrict__ B,
    const float* __restrict__ c, float* __restrict__ out)
{
    __shared__ __align__(16) float xs[32][68];  // [k][t]
    __shared__ __align__(16) float bs[32][68];  // [k][i]

    const int tid = threadIdx.x;
    const int t0 = blockIdx.x * 64;
    const int i0 = blockIdx.y * 64;
    const int tx = tid & 15;        // i direction (4 outputs)
    const int ty = tid >> 4;        // t direction (4 outputs)
    const int lr = tid >> 3;        // staging row 0..31
    const int lc = (tid & 7) << 2;  // staging k 0,4,...,28

    float acc[4][4] = {{0.f}};

    for (int k0 = 0; k0 < XD; k0 += 32) {
        const float4 xa = *(const float4*)&x[(size_t)(t0 + lr) * XD + k0 + lc];
        const float4 xb = *(const float4*)&x[(size_t)(t0 + lr + 32) * XD + k0 + lc];
        const float4 ba = *(const float4*)&B[(size_t)(i0 + lr) * XD + k0 + lc];
        const float4 bb = *(const float4*)&B[(size_t)(i0 + lr + 32) * XD + k0 + lc];
        __syncthreads();
        xs[lc + 0][lr] = xa.x; xs[lc + 1][lr] = xa.y; xs[lc + 2][lr] = xa.z; xs[lc + 3][lr] = xa.w;
        xs[lc + 0][lr + 32] = xb.x; xs[lc + 1][lr + 32] = xb.y; xs[lc + 2][lr + 32] = xb.z; xs[lc + 3][lr + 32] = xb.w;
        bs[lc + 0][lr] = ba.x; bs[lc + 1][lr] = ba.y; bs[lc + 2][lr] = ba.z; bs[lc + 3][lr] = ba.w;
        bs[lc + 0][lr + 32] = bb.x; bs[lc + 1][lr + 32] = bb.y; bs[lc + 2][lr + 32] = bb.z; bs[lc + 3][lr + 32] = bb.w;
        __syncthreads();
        #pragma unroll
        for (int k = 0; k < 32; ++k) {
            const float4 av = *(const float4*)&xs[k][ty << 2];
            const float4 bv = *(const float4*)&bs[k][tx << 2];
            const float am[4] = {av.x, av.y, av.z, av.w};
            const float bn[4] = {bv.x, bv.y, bv.z, bv.w};
            #pragma unroll
            for (int m = 0; m < 4; ++m)
                #pragma unroll
                for (int n = 0; n < 4; ++n)
                    acc[m][n] = fmaf(am[m], bn[n], acc[m][n]);
        }
    }

    #pragma unroll
    for (int m = 0; m < 4; ++m) {
        const int trow = t0 + (ty << 2) + m;
        #pragma unroll
        for (int n = 0; n < 4; ++n) {
            const int icol = i0 + (tx << 2) + n;
            out[(size_t)trow * HD + icol] = acc[m][n] + c[icol];
        }
    }
}

// ---------------------------------------------------------------------------
// Slot-ring init (d_ws is poisoned 0xAA before every launch).
// ring[3] holds h0 with tag 0; rings 0..2 get an impossible tag.
// ---------------------------------------------------------------------------
__global__ void init_slots_kernel(unsigned long long* slots, const float* h0)
{
    const int i = threadIdx.x;  // 1024 threads
    union { float f; unsigned u; } v; v.f = h0[i];
    slots[3 * HD + i] = (unsigned long long)v.u;          // tag 0 | h0 bits
    slots[0 * HD + i] = 0xFFFFFFFF00000000ull;
    slots[1 * HD + i] = 0xFFFFFFFF00000000ull;
    slots[2 * HD + i] = 0xFFFFFFFF00000000ull;
}

// ---------------------------------------------------------------------------
// Phase 2: tagged-slot scan. 64 blocks x 512 threads; wave w owns rows
// 16*bid + 2w and 16*bid + 2w + 1.
// ---------------------------------------------------------------------------
__global__ __launch_bounds__(512) void rnn_scan_kernel(
    const float* __restrict__ A_raw, float* out,
    unsigned long long* slots)
{
    const int tid = threadIdx.x;       // 0..511
    const int bid = blockIdx.x;        // 0..63
    const int wave = tid >> 6;         // 0..7
    const int lane = tid & 63;
    const int r0 = (bid << 4) + (wave << 1);   // rows r0, r0+1

    __shared__ float hlds[2][HD];

    // Effective A rows: A_eff[r][k] = 0.1*A_raw[r][k] + 0.9*(k==r)
    float aw0[16], aw1[16];
    #pragma unroll
    for (int j = 0; j < 16; ++j) {
        const int k = lane + (j << 6);
        float v0 = 0.1f * A_raw[(size_t)r0 * HD + k];
        float v1 = 0.1f * A_raw[(size_t)(r0 + 1) * HD + k];
        if (k == r0) v0 += 0.9f;
        if (k == r0 + 1) v1 += 0.9f;
        aw0[j] = v0; aw1[j] = v1;
    }

    // Prefetch Bx for t=0.
    float2 bxn = *(const float2*)&out[r0];

    for (int t = 0; t < T_STEPS; ++t) {
        const float2 bx = bxn;

        // Poll my two adjacent slots of h_{t-1}: ring[(t+3)&3], tag t.
        // One 16B L1/L2-bypass load per iteration (single LLC round trip).
        const unsigned long long* sp =
            slots + ((size_t)((t + 3) & 3) << 10) + (tid << 1);
        uint32x4 s;
        do {
            asm volatile(
                "global_load_dwordx4 %0, %1, off sc0 sc1\n\t"
                "s_waitcnt vmcnt(0)"
                : "=v"(s) : "v"(sp));
        } while (s.y != (unsigned)t || s.w != (unsigned)t);

        union { unsigned u; float f; } c0, c1; c0.u = s.x; c1.u = s.z;
        *(float2*)&hlds[t & 1][tid << 1] = make_float2(c0.f, c1.f);
        __syncthreads();

        // Prefetch next step's Bx while h is consumed.
        const int tn = (t + 1 < T_STEPS) ? (t + 1) : t;
        bxn = *(const float2*)&out[(size_t)tn * HD + r0];

        // Both rows' dot products from ONE pass over h in LDS.
        const float* hl = hlds[t & 1];
        float p0 = 0.f, p1 = 0.f;
        #pragma unroll
        for (int j = 0; j < 16; ++j) {
            const float hvj = hl[lane + (j << 6)];
            p0 = fmaf(aw0[j], hvj, p0);
            p1 = fmaf(aw1[j], hvj, p1);
        }

        // wave-wide sums (64 lanes)
        #pragma unroll
        for (int off = 32; off >= 1; off >>= 1) {
            p0 += __shfl_xor(p0, off, 64);
            p1 += __shfl_xor(p1, off, 64);
        }

        if (lane == 0) {
            const float h0n = tanhf(p0 + bx.x);
            const float h1n = tanhf(p1 + bx.y);
            *(float2*)&out[(size_t)t * HD + r0] = make_float2(h0n, h1n);
            union { float f; unsigned u; } u0, u1; u0.f = h0n; u1.f = h1n;
            uint32x4 pkt;
            pkt.x = u0.u; pkt.y = (unsigned)(t + 1);
            pkt.z = u1.u; pkt.w = (unsigned)(t + 1);
            unsigned long long* dp = slots + ((size_t)(t & 3) << 10) + r0;
            asm volatile(
                "global_store_dwordx4 %0, %1, off sc0 sc1"
                :: "v"(dp), "v"(pkt) : "memory");
        }
        // No grid barrier: tags + 4-deep ring + dataflow (skew <= 1) suffice.
        // LDS double buffer covers intra-block wave skew.
    }
}

// ---------------------------------------------------------------------------
extern "C" void kernel_launch(void* const* d_in, const int* in_sizes, int n_in,
                              void* d_out, int out_size, void* d_ws, size_t ws_size,
                              hipStream_t stream)
{
    const float* x     = (const float*)d_in[0];  // [16384, 512]
    const float* h0    = (const float*)d_in[1];  // [1024]
    const float* A_raw = (const float*)d_in[2];  // [1024, 1024]
    const float* B     = (const float*)d_in[3];  // [1024, 512]
    const float* c     = (const float*)d_in[4];  // [1024]
    float* out = (float*)d_out;                  // [16384, 1024]
    unsigned long long* slots = (unsigned long long*)d_ws;  // 4 x 1024 x 8B

    dim3 gemm_grid(T_STEPS / 64, HD / 64);       // 256 x 16
    gemm_bx_kernel<<<gemm_grid, 256, 0, stream>>>(x, B, c, out);
    init_slots_kernel<<<1, HD, 0, stream>>>(slots, h0);
    rnn_scan_kernel<<<64, 512, 0, stream>>>(A_raw, out, slots);
}